// Round 9
// baseline (51.418 us; speedup 1.0000x reference)
//
#include <hip/hip_runtime.h>

#define NPTS 2048
#define CH 32
#define KT 32                 // Taylor terms (validated round 8: absmax ~0)
#define NBLK 64
#define NTHR 512
#define RPB 32                // rows per block
#define LOG2E 1.4426950408889634f

#if defined(__has_builtin)
#if __has_builtin(__builtin_amdgcn_exp2f)
#define EXP2F(x) __builtin_amdgcn_exp2f(x)
#endif
#endif
#ifndef EXP2F
#define EXP2F(x) exp2f(x)
#endif

struct Params {
    const float *f_x, *x_grid, *qw, *lift_W, *lift_b, *pw_W, *pw_b, *kle, *kls;
    const float *p1W, *p1b, *p2W, *p2b, *p3W, *p3b;
    int* ctrl;                // barrier counters (128B apart), memset to 0 per call
    float* P;                 // 2 ping-pong partial buffers [2][NBLK][KT*CH]
    float* out;
};

__device__ __forceinline__ float gelu_tanh(float x) {
    float x3 = x * x * x;
    float u = 0.7978845608028654f * (x + 0.044715f * x3);
    return 0.5f * x * (1.0f + tanhf(u));
}

__global__ __launch_bounds__(NTHR, 1) void k_fused(Params p) {
    __shared__ float sWt[3][CH][CH];       // pw_W transposed [l][k][c]
    __shared__ float sW1t[CH][CH], sW2t[CH][CH];
    __shared__ float sb1[CH], sb2[CH], sW3v[CH];
    __shared__ float xrow[RPB], wrow[RPB];
    __shared__ float lgk[KT];              // log2(k!)
    __shared__ float fqb[2][RPB][CH];
    __shared__ float sS[RPB][CH], sLT[RPB][CH];
    __shared__ float sM[KT][CH];

    const int tid = threadIdx.x;
    const int b = blockIdx.x;
    const int c = tid & 31;
    const int r0 = tid >> 5;               // 0..15; thread covers rows r0, r0+16
    const int n0 = b * RPB;

    // ---- preload ----
    for (int i = tid; i < 3 * CH * CH; i += NTHR) {
        const int l = i >> 10, k = (i >> 5) & 31, cc = i & 31;
        sWt[l][k][cc] = p.pw_W[l * CH * CH + cc * CH + k];
    }
    for (int i = tid; i < CH * CH; i += NTHR) {
        const int k = i >> 5, cc = i & 31;
        sW1t[k][cc] = p.p1W[cc * CH + k];
        sW2t[k][cc] = p.p2W[cc * CH + k];
    }
    if (tid < CH) { sb1[tid] = p.p1b[tid]; sb2[tid] = p.p2b[tid]; sW3v[tid] = p.p3W[tid]; }
    if (tid < KT) lgk[tid] = lgammaf((float)tid + 1.0f) * LOG2E;
    if (tid < RPB) { xrow[tid] = p.x_grid[n0 + tid]; wrow[tid] = p.qw[n0 + tid]; }
    __syncthreads();

    // ---- lift (row-local) ----
    for (int rr = r0; rr < RPB; rr += 16) {
        float v = p.f_x[n0 + rr] * p.lift_W[c * 2] + xrow[rr] * p.lift_W[c * 2 + 1] + p.lift_b[c];
        fqb[0][rr][c] = gelu_tanh(v);
    }

    int cur = 0;
    for (int l = 0; l < 3; l++) {
        const float invl2 = expf(-2.0f * p.kle[l * CH + c]);
        const float nb2 = -0.5f * invl2 * LOG2E;   // exp2(x^2*nb2) = e^{-x^2/(2 ell^2)}
        const float sig2 = expf(2.0f * p.kls[l * CH + c]);
        __syncthreads();                   // fqb[cur] ready

        // stage A: s = e^{-xq^2/(2l^2)} * fq * w ;  lt = log2(xq/ell^2)
        for (int rr = r0; rr < RPB; rr += 16) {
            const float xq = xrow[rr];
            sS[rr][c] = EXP2F(xq * xq * nb2) * fqb[cur][rr][c] * wrow[rr];
            sLT[rr][c] = log2f(fmaxf(xq, 1e-30f) * invl2);
        }
        __syncthreads();

        // stage B: block-partial moments  Pb[k*CH+c] = sum_r exp2(k*lt - lg k!) * s
        float* Pb = p.P + (l & 1) * (NBLK * KT * CH) + b * (KT * CH);
        for (int it = tid; it < KT * CH; it += NTHR) {
            const int k = it >> 5, cc = it & 31;
            const float kf = (float)k, nl = -lgk[k];
            float a = 0.0f;
#pragma unroll
            for (int rr = 0; rr < RPB; rr++)
                a += EXP2F(fmaf(kf, sLT[rr][cc], nl)) * sS[rr][cc];
            Pb[it] = a;
        }

        // ---- arrive (release: flushes partials), hide skip-GEMM, then wait ----
        int* cnt = p.ctrl + l * 32;        // counters 128 B apart
        __syncthreads();                   // all threads' Pb stores drained
        if (tid == 0)
            __hip_atomic_fetch_add(cnt, 1, __ATOMIC_RELEASE, __HIP_MEMORY_SCOPE_AGENT);

        float skipA = p.pw_b[l * CH + c], skipB = skipA;
#pragma unroll
        for (int k = 0; k < CH; k++) {
            skipA = fmaf(fqb[cur][r0][k], sWt[l][k][c], skipA);
            skipB = fmaf(fqb[cur][r0 + 16][k], sWt[l][k][c], skipB);
        }

        if (tid == 0) {
            while (__hip_atomic_load(cnt, __ATOMIC_RELAXED, __HIP_MEMORY_SCOPE_AGENT) < NBLK)
                __builtin_amdgcn_s_sleep(4);
        }
        __syncthreads();

        // stage C: reduce all partials (agent-scope u64 atomic loads: fresh, deterministic)
        {
            const unsigned long long* P0 =
                (const unsigned long long*)(p.P + (l & 1) * (NBLK * KT * CH));
            const int it = tid;            // KT*CH/2 == NTHR
            float ax = 0.0f, ay = 0.0f;
#pragma unroll 4
            for (int b2 = 0; b2 < NBLK; b2++) {
                unsigned long long v = __hip_atomic_load(P0 + b2 * (KT * CH / 2) + it,
                                                         __ATOMIC_RELAXED,
                                                         __HIP_MEMORY_SCOPE_AGENT);
                union { unsigned long long u; float f[2]; } cv; cv.u = v;
                ax += cv.f[0]; ay += cv.f[1];
            }
            sM[(2 * it) >> 5][(2 * it) & 31] = ax;
            sM[(2 * it) >> 5][(2 * it + 1) & 31] = ay;
        }
        __syncthreads();

        // stage D: Horner + combine (skip already in regs)
        {
            const float xnA = xrow[r0], xnB = xrow[r0 + 16];
            float PA = sM[KT - 1][c], PB = PA;
#pragma unroll
            for (int k = KT - 2; k >= 0; k--) {
                PA = fmaf(PA, xnA, sM[k][c]);
                PB = fmaf(PB, xnB, sM[k][c]);
            }
            float vA = skipA + sig2 * EXP2F(xnA * xnA * nb2) * PA;
            float vB = skipB + sig2 * EXP2F(xnB * xnB * nb2) * PB;
            if (l < 2) { vA = gelu_tanh(vA); vB = gelu_tanh(vB); }
            fqb[cur ^ 1][r0][c] = vA;
            fqb[cur ^ 1][r0 + 16][c] = vB;
        }
        cur ^= 1;
    }
    __syncthreads();

    // ---- projection head (row-local; reuse sS/sLT) ----
    for (int rr = r0; rr < RPB; rr += 16) {
        float s = sb1[c];
#pragma unroll
        for (int k = 0; k < CH; k++) s = fmaf(fqb[cur][rr][k], sW1t[k][c], s);
        sS[rr][c] = gelu_tanh(s);
    }
    __syncthreads();
    for (int rr = r0; rr < RPB; rr += 16) {
        float s = sb2[c];
#pragma unroll
        for (int k = 0; k < CH; k++) s = fmaf(sS[rr][k], sW2t[k][c], s);
        sLT[rr][c] = gelu_tanh(s);
    }
    __syncthreads();
    if (tid < RPB) {
        float s = p.p3b[0];
#pragma unroll
        for (int k = 0; k < CH; k++) s = fmaf(sLT[tid][k], sW3v[k], s);
        p.out[n0 + tid] = s;
    }
}

extern "C" void kernel_launch(void* const* d_in, const int* in_sizes, int n_in,
                              void* d_out, int out_size, void* d_ws, size_t ws_size,
                              hipStream_t stream) {
    Params p;
    p.f_x    = (const float*)d_in[0];
    p.x_grid = (const float*)d_in[1];
    p.qw     = (const float*)d_in[2];
    p.lift_W = (const float*)d_in[3];
    p.lift_b = (const float*)d_in[4];
    p.pw_W   = (const float*)d_in[5];
    p.pw_b   = (const float*)d_in[6];
    p.kle    = (const float*)d_in[7];
    p.kls    = (const float*)d_in[8];
    p.p1W    = (const float*)d_in[9];
    p.p1b    = (const float*)d_in[10];
    p.p2W    = (const float*)d_in[11];
    p.p2b    = (const float*)d_in[12];
    p.p3W    = (const float*)d_in[13];
    p.p3b    = (const float*)d_in[14];

    p.ctrl   = (int*)d_ws;
    p.P      = (float*)((char*)d_ws + 512);
    p.out    = (float*)d_out;

    hipMemsetAsync(d_ws, 0, 512, stream);      // zero barrier counters (capture-legal)
    k_fused<<<dim3(NBLK), dim3(NTHR), 0, stream>>>(p);
}

// Round 10
// 42.697 us; speedup vs baseline: 1.2043x; 1.2043x over previous
//
#include <hip/hip_runtime.h>

#define NPTS 2048
#define CH 32
#define KT 32                 // Taylor terms (validated rounds 8-9: absmax 0)
#define NBLK 32
#define NTHR 512
#define RPB 64                // rows per block
#define LOG2E 1.4426950408889634f

#if defined(__has_builtin)
#if __has_builtin(__builtin_amdgcn_exp2f)
#define EXP2F(x) __builtin_amdgcn_exp2f(x)
#endif
#endif
#ifndef EXP2F
#define EXP2F(x) exp2f(x)
#endif

struct Params {
    const float *f_x, *x_grid, *qw, *lift_W, *lift_b, *pw_W, *pw_b, *kle, *kls;
    const float *p1W, *p1b, *p2W, *p2b, *p3W, *p3b;
    int* ctrl;                // barrier counters (128B apart), memset to 0 per call
    float* P;                 // 2 ping-pong partial buffers [2][NBLK][KT*CH]
    float* out;
};

__device__ __forceinline__ float gelu_tanh(float x) {
    float x3 = x * x * x;
    float u = 0.7978845608028654f * (x + 0.044715f * x3);
    return 0.5f * x * (1.0f + tanhf(u));
}

__global__ __launch_bounds__(NTHR, 1) void k_fused(Params p) {
    __shared__ float sWt[3][CH][CH];       // pw_W transposed [l][k][c]
    __shared__ float sW1t[CH][CH], sW2t[CH][CH];
    __shared__ float sb1[CH], sb2[CH], sW3v[CH];
    __shared__ float xrow[RPB], wrow[RPB];
    __shared__ float lgk[KT];              // log2(k!)
    __shared__ float fqb[2][RPB][CH];      // 16 KB
    __shared__ float sS[RPB][CH], sLT[RPB][CH];   // 16 KB
    __shared__ float sM[KT][CH];

    const int tid = threadIdx.x;
    const int b = blockIdx.x;
    const int c = tid & 31;
    const int r0 = tid >> 5;               // 0..15; thread covers rows r0+16j, j=0..3
    const int n0 = b * RPB;

    // ---- preload ----
    for (int i = tid; i < 3 * CH * CH; i += NTHR) {
        const int l = i >> 10, k = (i >> 5) & 31, cc = i & 31;
        sWt[l][k][cc] = p.pw_W[l * CH * CH + cc * CH + k];
    }
    for (int i = tid; i < CH * CH; i += NTHR) {
        const int k = i >> 5, cc = i & 31;
        sW1t[k][cc] = p.p1W[cc * CH + k];
        sW2t[k][cc] = p.p2W[cc * CH + k];
    }
    if (tid < CH) { sb1[tid] = p.p1b[tid]; sb2[tid] = p.p2b[tid]; sW3v[tid] = p.p3W[tid]; }
    if (tid < KT) lgk[tid] = lgammaf((float)tid + 1.0f) * LOG2E;
    if (tid < RPB) { xrow[tid] = p.x_grid[n0 + tid]; wrow[tid] = p.qw[n0 + tid]; }
    __syncthreads();

    // ---- lift (row-local) ----
#pragma unroll
    for (int j = 0; j < 4; j++) {
        const int rr = r0 + 16 * j;
        float v = p.f_x[n0 + rr] * p.lift_W[c * 2] + xrow[rr] * p.lift_W[c * 2 + 1] + p.lift_b[c];
        fqb[0][rr][c] = gelu_tanh(v);
    }

    int cur = 0;
    for (int l = 0; l < 3; l++) {
        const float invl2 = expf(-2.0f * p.kle[l * CH + c]);
        const float nb2 = -0.5f * invl2 * LOG2E;   // exp2(x^2*nb2) = e^{-x^2/(2 ell^2)}
        const float sig2 = expf(2.0f * p.kls[l * CH + c]);
        __syncthreads();                   // fqb[cur] ready

        // stage A: s = e^{-xq^2/(2l^2)} * fq * w ;  lt = log2(xq/ell^2)
#pragma unroll
        for (int j = 0; j < 4; j++) {
            const int rr = r0 + 16 * j;
            const float xq = xrow[rr];
            sS[rr][c] = EXP2F(xq * xq * nb2) * fqb[cur][rr][c] * wrow[rr];
            sLT[rr][c] = log2f(fmaxf(xq, 1e-30f) * invl2);
        }
        __syncthreads();

        // stage B: block-partial moments; thread handles items tid and tid+512
        float* Pb = p.P + (l & 1) * (NBLK * KT * CH) + b * (KT * CH);
        {
            const int k0 = tid >> 5;           // 0..15
            const int k1 = k0 + 16;
            const float kf0 = (float)k0, nl0 = -lgk[k0];
            const float kf1 = (float)k1, nl1 = -lgk[k1];
            float a0 = 0.0f, a1 = 0.0f;
#pragma unroll
            for (int rr = 0; rr < RPB; rr++) {
                const float s = sS[rr][c], lt = sLT[rr][c];
                a0 += EXP2F(fmaf(kf0, lt, nl0)) * s;
                a1 += EXP2F(fmaf(kf1, lt, nl1)) * s;
            }
            Pb[k0 * CH + c] = a0;
            Pb[k1 * CH + c] = a1;
        }

        // ---- arrive (release flushes partials), hide skip-GEMM, then wait ----
        int* cnt = p.ctrl + l * 32;        // counters 128 B apart
        __syncthreads();                   // all threads' Pb stores drained
        if (tid == 0)
            __hip_atomic_fetch_add(cnt, 1, __ATOMIC_RELEASE, __HIP_MEMORY_SCOPE_AGENT);

        float skip[4];
#pragma unroll
        for (int j = 0; j < 4; j++) skip[j] = p.pw_b[l * CH + c];
#pragma unroll
        for (int k = 0; k < CH; k++) {
            const float wv = sWt[l][k][c];
#pragma unroll
            for (int j = 0; j < 4; j++)
                skip[j] = fmaf(fqb[cur][r0 + 16 * j][k], wv, skip[j]);
        }

        if (tid == 0) {
            while (__hip_atomic_load(cnt, __ATOMIC_RELAXED, __HIP_MEMORY_SCOPE_AGENT) < NBLK)
                __builtin_amdgcn_s_sleep(1);
        }
        __syncthreads();

        // stage C: reduce all partials — 32 agent-scope u64 loads, 16-deep ILP
        {
            const unsigned long long* P0 =
                (const unsigned long long*)(p.P + (l & 1) * (NBLK * KT * CH));
            float ax = 0.0f, ay = 0.0f;
#pragma unroll
            for (int h = 0; h < 2; h++) {
                unsigned long long v[16];
#pragma unroll
                for (int u = 0; u < 16; u++)
                    v[u] = __hip_atomic_load(P0 + (h * 16 + u) * (KT * CH / 2) + tid,
                                             __ATOMIC_RELAXED, __HIP_MEMORY_SCOPE_AGENT);
#pragma unroll
                for (int u = 0; u < 16; u++) {
                    union { unsigned long long q; float f[2]; } cv; cv.q = v[u];
                    ax += cv.f[0]; ay += cv.f[1];
                }
            }
            sM[tid >> 4][(2 * tid) & 31] = ax;
            sM[tid >> 4][(2 * tid + 1) & 31] = ay;
        }
        __syncthreads();

        // stage D: Horner + combine (skip already in regs)
        {
            float Ph[4];
#pragma unroll
            for (int j = 0; j < 4; j++) Ph[j] = sM[KT - 1][c];
#pragma unroll
            for (int k = KT - 2; k >= 0; k--) {
                const float mk = sM[k][c];
#pragma unroll
                for (int j = 0; j < 4; j++) Ph[j] = fmaf(Ph[j], xrow[r0 + 16 * j], mk);
            }
#pragma unroll
            for (int j = 0; j < 4; j++) {
                const int rr = r0 + 16 * j;
                const float xn = xrow[rr];
                float v = skip[j] + sig2 * EXP2F(xn * xn * nb2) * Ph[j];
                if (l < 2) v = gelu_tanh(v);
                fqb[cur ^ 1][rr][c] = v;
            }
        }
        cur ^= 1;
    }
    __syncthreads();

    // ---- projection head (row-local; reuse sS/sLT) ----
#pragma unroll
    for (int j = 0; j < 4; j++) {
        const int rr = r0 + 16 * j;
        float s = sb1[c];
#pragma unroll
        for (int k = 0; k < CH; k++) s = fmaf(fqb[cur][rr][k], sW1t[k][c], s);
        sS[rr][c] = gelu_tanh(s);
    }
    __syncthreads();
#pragma unroll
    for (int j = 0; j < 4; j++) {
        const int rr = r0 + 16 * j;
        float s = sb2[c];
#pragma unroll
        for (int k = 0; k < CH; k++) s = fmaf(sS[rr][k], sW2t[k][c], s);
        sLT[rr][c] = gelu_tanh(s);
    }
    __syncthreads();
    if (tid < RPB) {
        float s = p.p3b[0];
#pragma unroll
        for (int k = 0; k < CH; k++) s = fmaf(sLT[tid][k], sW3v[k], s);
        p.out[n0 + tid] = s;
    }
}

extern "C" void kernel_launch(void* const* d_in, const int* in_sizes, int n_in,
                              void* d_out, int out_size, void* d_ws, size_t ws_size,
                              hipStream_t stream) {
    Params p;
    p.f_x    = (const float*)d_in[0];
    p.x_grid = (const float*)d_in[1];
    p.qw     = (const float*)d_in[2];
    p.lift_W = (const float*)d_in[3];
    p.lift_b = (const float*)d_in[4];
    p.pw_W   = (const float*)d_in[5];
    p.pw_b   = (const float*)d_in[6];
    p.kle    = (const float*)d_in[7];
    p.kls    = (const float*)d_in[8];
    p.p1W    = (const float*)d_in[9];
    p.p1b    = (const float*)d_in[10];
    p.p2W    = (const float*)d_in[11];
    p.p2b    = (const float*)d_in[12];
    p.p3W    = (const float*)d_in[13];
    p.p3b    = (const float*)d_in[14];

    p.ctrl   = (int*)d_ws;
    p.P      = (float*)((char*)d_ws + 512);
    p.out    = (float*)d_out;

    hipMemsetAsync(d_ws, 0, 512, stream);      // zero barrier counters (capture-legal)
    k_fused<<<dim3(NBLK), dim3(NTHR), 0, stream>>>(p);
}